// Round 5
// baseline (1059.918 us; speedup 1.0000x reference)
//
#include <hip/hip_runtime.h>
#include <hip/hip_bf16.h>
#include <stdint.h>
#include <type_traits>

// Problem constants (S=2048, B=4, H=1024, F=4096, E=8)
#define SB   8192
#define HDIM 1024
#define FDIM 4096
#define EDIM 8

typedef __bf16 bf16x8 __attribute__((ext_vector_type(8)));
typedef float  f32x4  __attribute__((ext_vector_type(4)));

__device__ __forceinline__ void g2l16(const void* g, void* l) {
  __builtin_amdgcn_global_load_lds(
      (const __attribute__((address_space(1))) uint32_t*)g,
      (__attribute__((address_space(3))) uint32_t*)l, 16, 0, 0);
}

__device__ __forceinline__ unsigned short f2bf(float f) {
  __hip_bfloat16 b = __float2bfloat16(f);
  return *reinterpret_cast<unsigned short*>(&b);
}

// inline-asm ds_read_b128 with compile-time offset immediate.
template <int IMM>
__device__ __forceinline__ bf16x8 lds_rd128(int addr) {
  static_assert(IMM >= 0 && IMM < 65536, "ds offset");
  bf16x8 r;
  asm volatile("ds_read_b128 %0, %1 offset:%2" : "=v"(r) : "v"(addr), "n"(IMM));
  return r;
}

// ---------------- cast fp32 -> bf16 (vectorized) ----------------
__global__ void cast_bf16_kernel(const float4* __restrict__ in,
                                 ushort4* __restrict__ out, int n4) {
  int i = blockIdx.x * blockDim.x + threadIdx.x;
  if (i < n4) {
    float4 v = in[i];
    ushort4 o;
    o.x = f2bf(v.x); o.y = f2bf(v.y); o.z = f2bf(v.z); o.w = f2bf(v.w);
    out[i] = o;
  }
}

// ---------------- lambda: lam[e] = gb2[e] + dot(colsum, gw2[e,:]) / 8192 ----
__global__ void lam_kernel(const float* __restrict__ colsum,
                           const float* __restrict__ gw2,
                           const float* __restrict__ gb2,
                           float* __restrict__ lam) {
  __shared__ float red[256];
  const int tid = threadIdx.x;
  for (int e = 0; e < EDIM; ++e) {
    float p = 0.f;
    for (int h = tid; h < HDIM; h += 256) p += colsum[h] * gw2[e * HDIM + h];
    red[tid] = p;
    __syncthreads();
    for (int s = 128; s > 0; s >>= 1) {
      if (tid < s) red[tid] += red[tid + s];
      __syncthreads();
    }
    if (tid == 0) lam[e] = gb2[e] + red[0] * (1.f / 8192.f);
    __syncthreads();
  }
}

// ---------------- merge weights: out_bf16 = base + sum_e lam[e]*tv[e] ------
__global__ void merge_w_kernel(const float4* __restrict__ base,
                               const float4* __restrict__ tv,
                               const float* __restrict__ lam,
                               ushort4* __restrict__ outw, int n4) {
  int i = blockIdx.x * blockDim.x + threadIdx.x;
  if (i >= n4) return;
  float l[EDIM];
#pragma unroll
  for (int e = 0; e < EDIM; ++e) l[e] = lam[e];
  float4 v = base[i];
#pragma unroll
  for (int e = 0; e < EDIM; ++e) {
    float4 t = tv[(size_t)e * n4 + i];
    v.x += l[e] * t.x; v.y += l[e] * t.y; v.z += l[e] * t.z; v.w += l[e] * t.w;
  }
  ushort4 o;
  o.x = f2bf(v.x); o.y = f2bf(v.y); o.z = f2bf(v.z); o.w = f2bf(v.w);
  outw[i] = o;
}

// ---------------- merge biases (fp32 out, tiny) ----------------------------
__global__ void merge_b_kernel(const float* __restrict__ base,
                               const float* __restrict__ tv,
                               const float* __restrict__ lam,
                               float* __restrict__ outb, int n) {
  int i = blockIdx.x * blockDim.x + threadIdx.x;
  if (i >= n) return;
  float v = base[i];
#pragma unroll
  for (int e = 0; e < EDIM; ++e) v += lam[e] * tv[(size_t)e * n + i];
  outb[i] = v;
}

// ---------------------------------------------------------------------------
// 8-phase pipelined MFMA bt-GEMM (R2 structure, harness-verified twice).
// ABL diagnostic bits (rule #17-safe: MFMA+epilogue always live):
//   bit0 (DO_RD): in-loop ds_reads   bit1 (DO_ST): staging + vmcnt protocol
// ABL=3 is the real kernel (identical to R2).  ABL<3 instances are launched
// only as timing ablations into scratch (output overwritten afterwards).
template <int MODE, int BN, int ABL = 3>
__global__ void __launch_bounds__(512, 2)
gemm8p(const ushort* __restrict__ A, const ushort* __restrict__ B,
       const float* __restrict__ bias, void* __restrict__ Cout,
       int M, int N, int K) {
  constexpr bool DO_RD = (ABL & 1) != 0;
  constexpr bool DO_ST = (ABL & 2) != 0;
  constexpr int NF   = BN / 64;          // per-wave n-frags (4 or 2)
  constexpr int AREG = 256 * 32;         // elems per A k-region (16KB)
  constexpr int BREG = BN * 32;          // elems per B k-region
  constexpr int BUFSZ = 2 * AREG + 2 * BREG;  // elems per buffer
  constexpr int BUFB  = BUFSZ * 2;            // bytes per buffer
  constexpr int UPT  = (BN == 256) ? 4 : 3;   // stage units per K-tile
  constexpr int U2   = (BN == 256) ? 3 : 2;   // "last B unit" id
  extern __shared__ __align__(16) ushort smem[];
  (void)M;

  const int tid  = threadIdx.x;
  const int lane = tid & 63;
  const int wave = tid >> 6;
  const int wm = wave >> 2, wn = wave & 3;
  const int lr = lane & 15, lq = lane >> 4;

  // XCD-aware swizzle (gridDim.y % 8 == 0)
  const int bid = blockIdx.y * gridDim.x + blockIdx.x;
  const int gx  = gridDim.x;
  const int Yc  = gridDim.y >> 3;
  const int xcd = bid & 7;
  const int tt  = bid >> 3;
  const int tq  = tt / gx;
  const int ty  = xcd * Yc + tq;
  const int tx  = tt - tq * gx;
  const int m0 = ty * 256, n0 = tx * BN;

  const int NT = K >> 6;  // K-tiles (BK=64); even, >= 4 for all our shapes

  // ---- per-lane LDS read base addresses (swizzle term lane-constant in mi)
  const uint32_t smemBase =
      (uint32_t)(uintptr_t)(__attribute__((address_space(3))) ushort*)smem;
  const int rowAl = wm * 128 + lr;
  const int vA0 = (int)smemBase + rowAl * 64 + ((lq ^ ((rowAl >> 1) & 3)) << 4);
  const int vA1 = vA0 + BUFB;
  const int rowBl = wn * (BN / 4) + lr;
  const int vB0 = (int)smemBase + 2 * AREG * 2 + rowBl * 64 +
                  ((lq ^ ((rowBl >> 1) & 3)) << 4);
  const int vB1 = vB0 + BUFB;

  // ---- per-thread staging pointers (global src pre-swizzled, LDS dest
  // lane-linear; rule 21).  Swizzle col is identical for row and row+128.
  const int rr = tid >> 2;
  const int colS = ((tid & 3) ^ ((rr >> 1) & 3)) * 8;
  const ushort* gA0p = A + (size_t)(m0 + rr) * K + colS;
  const ushort* gA1p = gA0p + (size_t)128 * K;
  const ushort* gB0p = B + (size_t)(n0 + rr) * K + colS;
  const ushort* gB1p = gB0p + (size_t)128 * K;  // used only when BN==256
  ushort* lds0 = smem + tid * 8;

  f32x4 acc[8][NF];
#pragma unroll
  for (int i = 0; i < 8; ++i)
#pragma unroll
    for (int n = 0; n < NF; ++n)
#pragma unroll
      for (int r = 0; r < 4; ++r) acc[i][n][r] = 0.f;

  bf16x8 bfr[NF];
  bf16x8 afr[4];

  // stage one unit (2 x global_load_lds_dwordx4 per thread = 16KB)
  auto stage_unit = [&](int buf, int u, int kt) {
    if constexpr (DO_ST) {
      const int bo = buf * BUFSZ;
      const int kk = kt * 64;
      if (u < 2) {
        ushort* l = lds0 + bo + u * AREG;
        g2l16(gA0p + kk + u * 32, l);
        g2l16(gA1p + kk + u * 32, l + 4096);
      } else if (BN == 256) {
        const int ks = u - 2;
        ushort* l = lds0 + bo + 2 * AREG + ks * BREG;
        g2l16(gB0p + kk + ks * 32, l);
        g2l16(gB1p + kk + ks * 32, l + 4096);
      } else {  // BN==128: both k-subtiles of B in one unit
        ushort* l = lds0 + bo + 2 * AREG;
        g2l16(gB0p + kk, l);
        g2l16(gB0p + kk + 32, l + 4096);
      }
    }
  };

  // one phase: reads (DO_RD), stage, barrier, lgkmcnt(0), MFMA, tail, barrier
  auto do_phase = [&](auto bufc, auto ksc, auto mhc, auto&& stage_fn, int tail) {
    constexpr int BUF = decltype(bufc)::value;
    constexpr int KS  = decltype(ksc)::value;
    constexpr int MH  = decltype(mhc)::value;
    if constexpr (DO_RD) {
      if constexpr (MH == 0) {
        const int vBb = BUF ? vB1 : vB0;
        bfr[0] = lds_rd128<KS * (BN * 64) + 0 * 1024>(vBb);
        bfr[1] = lds_rd128<KS * (BN * 64) + 1 * 1024>(vBb);
        if constexpr (NF == 4) {
          bfr[2] = lds_rd128<KS * (BN * 64) + 2 * 1024>(vBb);
          bfr[3] = lds_rd128<KS * (BN * 64) + 3 * 1024>(vBb);
        }
      }
      const int vAb = BUF ? vA1 : vA0;
      afr[0] = lds_rd128<KS * 16384 + (MH * 4 + 0) * 1024>(vAb);
      afr[1] = lds_rd128<KS * 16384 + (MH * 4 + 1) * 1024>(vAb);
      afr[2] = lds_rd128<KS * 16384 + (MH * 4 + 2) * 1024>(vAb);
      afr[3] = lds_rd128<KS * 16384 + (MH * 4 + 3) * 1024>(vAb);
    }
    stage_fn();
    __builtin_amdgcn_sched_barrier(0);
    __builtin_amdgcn_s_barrier();
    asm volatile("s_waitcnt lgkmcnt(0)");
    __builtin_amdgcn_sched_barrier(0);
    __builtin_amdgcn_s_setprio(1);
#pragma unroll
    for (int i = 0; i < 4; ++i)
#pragma unroll
      for (int n = 0; n < NF; ++n)
        acc[MH * 4 + i][n] = __builtin_amdgcn_mfma_f32_16x16x32_bf16(
            afr[i], bfr[n], acc[MH * 4 + i][n], 0, 0, 0);
    __builtin_amdgcn_s_setprio(0);
    __builtin_amdgcn_sched_barrier(0);
    const int tl = DO_ST ? tail : -1;
    if (tl == -1) {
      __builtin_amdgcn_s_barrier();
    } else if (tl == 4) {
      asm volatile("s_waitcnt vmcnt(4)");
      __builtin_amdgcn_s_barrier();
    } else if (tl == 2) {
      asm volatile("s_waitcnt vmcnt(2)");
      __builtin_amdgcn_s_barrier();
    } else {
      asm volatile("s_waitcnt vmcnt(0)");
      __builtin_amdgcn_s_barrier();
    }
    __builtin_amdgcn_sched_barrier(0);
  };

  // ---- prologue: tile0 fully, tile1 first units; leave steady-state loads
  // in flight (matches p1-entry state: A-k0 + B-k0 of next tile in flight)
  if constexpr (DO_ST) {
#pragma unroll
    for (int u = 0; u < UPT; ++u) stage_unit(0, u, 0);
    stage_unit(1, 0, 1);
    if (BN == 256) stage_unit(1, 2, 1);
    __builtin_amdgcn_sched_barrier(0);
    if constexpr (BN == 256) asm volatile("s_waitcnt vmcnt(4)");
    else                     asm volatile("s_waitcnt vmcnt(2)");
  }
  __builtin_amdgcn_s_barrier();
  __builtin_amdgcn_sched_barrier(0);
  if constexpr (!DO_RD) {
    // one-time operand load so MFMAs have live, register-resident frags
    bfr[0] = lds_rd128<0>(vB0);
    bfr[1] = lds_rd128<1024>(vB0);
    if constexpr (NF == 4) {
      bfr[2] = lds_rd128<2048>(vB0);
      bfr[3] = lds_rd128<3072>(vB0);
    }
    afr[0] = lds_rd128<0>(vA0);
    afr[1] = lds_rd128<1024>(vA0);
    afr[2] = lds_rd128<2048>(vA0);
    afr[3] = lds_rd128<3072>(vA0);
    asm volatile("s_waitcnt lgkmcnt(0)");
    __builtin_amdgcn_sched_barrier(0);
  }

  using I0 = std::integral_constant<int, 0>;
  using I1 = std::integral_constant<int, 1>;
  constexpr int LEAD = (BN == 256) ? 4 : 2;

  auto iter2 = [&](int t, auto lastc) {
    constexpr bool LAST = decltype(lastc)::value;
    do_phase(I0{}, I0{}, I0{}, [&] { stage_unit(1, 1, t + 1); }, -1);
    do_phase(I0{}, I0{}, I1{}, [&] { stage_unit(1, U2, t + 1); }, -1);
    do_phase(I0{}, I1{}, I0{}, [&] { if (!LAST) stage_unit(0, 0, t + 2); }, -1);
    do_phase(I0{}, I1{}, I1{},
             [&] { if (!LAST && BN == 256) stage_unit(0, 2, t + 2); },
             LAST ? 0 : LEAD);
    do_phase(I1{}, I0{}, I0{}, [&] { if (!LAST) stage_unit(0, 1, t + 2); }, -1);
    do_phase(I1{}, I0{}, I1{}, [&] { if (!LAST) stage_unit(0, U2, t + 2); }, -1);
    do_phase(I1{}, I1{}, I0{}, [&] { if (!LAST) stage_unit(1, 0, t + 3); }, -1);
    do_phase(I1{}, I1{}, I1{},
             [&] { if (!LAST && BN == 256) stage_unit(1, 2, t + 3); },
             LAST ? -1 : LEAD);
  };

  int t = 0;
  for (; t < NT - 2; t += 2) iter2(t, std::integral_constant<bool, false>{});
  iter2(t, std::integral_constant<bool, true>{});

  // ---- epilogue.  C/D layout (verified m89/m91): col=ni*16+lr, row=lq*4+r.
  const int gm = m0 + wm * 128;
  const int gn = n0 + wn * (BN / 4);
  if constexpr (MODE == 0) {
    float* colsum = (float*)Cout;
#pragma unroll
    for (int ni = 0; ni < NF; ++ni) {
      const int col = gn + ni * 16 + lr;
      const float bv = bias[col];
      float p = 0.f;
#pragma unroll
      for (int mi = 0; mi < 8; ++mi)
#pragma unroll
        for (int r = 0; r < 4; ++r) {
          float v = acc[mi][ni][r] + bv;
          p += v > 0.f ? v : 0.f;
        }
      p += __shfl_xor(p, 16);
      p += __shfl_xor(p, 32);
      if (lq == 0) atomicAdd(&colsum[col], p);
    }
  } else if constexpr (MODE == 1) {
    __hip_bfloat16* C = (__hip_bfloat16*)Cout;
#pragma unroll
    for (int ni = 0; ni < NF; ++ni) {
      const int col = gn + ni * 16 + lr;
      const float bv = bias[col];
#pragma unroll
      for (int mi = 0; mi < 8; ++mi)
#pragma unroll
        for (int r = 0; r < 4; ++r) {
          const int row = gm + mi * 16 + lq * 4 + r;
          float v = acc[mi][ni][r] + bv;
          v = v > 0.f ? v : 0.f;
          C[(size_t)row * N + col] = __float2bfloat16(v);
        }
    }
  } else {
    float* C = (float*)Cout;
#pragma unroll
    for (int ni = 0; ni < NF; ++ni) {
      const int col = gn + ni * 16 + lr;
      const float bv = bias[col];
#pragma unroll
      for (int mi = 0; mi < 8; ++mi)
#pragma unroll
        for (int r = 0; r < 4; ++r) {
          const int row = gm + mi * 16 + lq * 4 + r;
          C[(size_t)row * N + col] = acc[mi][ni][r] + bv;
        }
    }
  }
}

// ---------------------------------------------------------------------------
extern "C" void kernel_launch(void* const* d_in, const int* in_sizes, int n_in,
                              void* d_out, int out_size, void* d_ws, size_t ws_size,
                              hipStream_t stream) {
  const float* X   = (const float*)d_in[0];   // [S,B,H]
  const float* gw1 = (const float*)d_in[1];   // [H,H]
  const float* gb1 = (const float*)d_in[2];   // [H]
  const float* gw2 = (const float*)d_in[3];   // [E,H]
  const float* gb2 = (const float*)d_in[4];   // [E]
  const float* bw1 = (const float*)d_in[5];   // [F,H]
  const float* bb1 = (const float*)d_in[6];   // [F]
  const float* bw2 = (const float*)d_in[7];   // [H,F]
  const float* bb2 = (const float*)d_in[8];   // [H]
  const float* tw1 = (const float*)d_in[9];   // [E,F,H]
  const float* tb1 = (const float*)d_in[10];  // [E,F]
  const float* tw2 = (const float*)d_in[11];  // [E,H,F]
  const float* tb2 = (const float*)d_in[12];  // [E,H]
  float* out = (float*)d_out;                 // [S,B,H]

  // one-time: allow >64KB dynamic LDS for the pipelined GEMMs + diagnostics
  static bool s_attr = false;
  if (!s_attr) {
    (void)hipFuncSetAttribute(reinterpret_cast<const void*>(gemm8p<0, 128>),
                              hipFuncAttributeMaxDynamicSharedMemorySize, 98304);
    (void)hipFuncSetAttribute(reinterpret_cast<const void*>(gemm8p<2, 128>),
                              hipFuncAttributeMaxDynamicSharedMemorySize, 98304);
    (void)hipFuncSetAttribute(reinterpret_cast<const void*>(gemm8p<1, 256>),
                              hipFuncAttributeMaxDynamicSharedMemorySize, 131072);
    (void)hipFuncSetAttribute(reinterpret_cast<const void*>(gemm8p<1, 256, 0>),
                              hipFuncAttributeMaxDynamicSharedMemorySize, 131072);
    (void)hipFuncSetAttribute(reinterpret_cast<const void*>(gemm8p<1, 256, 1>),
                              hipFuncAttributeMaxDynamicSharedMemorySize, 131072);
    (void)hipFuncSetAttribute(reinterpret_cast<const void*>(gemm8p<1, 256, 2>),
                              hipFuncAttributeMaxDynamicSharedMemorySize, 131072);
    s_attr = true;
  }

  // workspace carve (256B aligned)
  size_t off = 0;
  auto carve = [&](size_t bytes) -> void* {
    void* p = (char*)d_ws + off;
    off += (bytes + 255) & ~(size_t)255;
    return p;
  };
  ushort* Xbf   = (ushort*)carve((size_t)SB * HDIM * 2);     // X in bf16
  ushort* gw1bf = (ushort*)carve((size_t)HDIM * HDIM * 2);   // gate w1 bf16
  ushort* w1m   = (ushort*)carve((size_t)FDIM * HDIM * 2);   // merged w1 bf16
  ushort* w2m   = (ushort*)carve((size_t)HDIM * FDIM * 2);   // merged w2 bf16
  ushort* hbuf  = (ushort*)carve((size_t)SB * FDIM * 2);     // h bf16
  float* b1m    = (float*)carve(FDIM * 4);
  float* b2m    = (float*)carve(HDIM * 4);
  float* colsum = (float*)carve(HDIM * 4);
  float* lam    = (float*)carve(EDIM * 4);

  // 0) DIAGNOSTIC ABLATIONS (timing only; hbuf is fully rewritten by the real
  //    GEMM6 below, so numerics are unaffected).  K=4096 so they rank in the
  //    top-5 profile table.  Inputs are raw workspace bytes (values
  //    irrelevant; MFMA timing is data-independent).
  {
    const ushort* Ad = (const ushort*)d_ws;
    const ushort* Bd = (const ushort*)d_ws;
    gemm8p<1, 256, 0><<<dim3(16, 32), 512, 131072, stream>>>(
        Ad, Bd, b1m, hbuf, SB, FDIM, 4096);  // D: MFMA+barriers only
    gemm8p<1, 256, 1><<<dim3(16, 32), 512, 131072, stream>>>(
        Ad, Bd, b1m, hbuf, SB, FDIM, 4096);  // B: +ds_reads
    gemm8p<1, 256, 2><<<dim3(16, 32), 512, 131072, stream>>>(
        Ad, Bd, b1m, hbuf, SB, FDIM, 4096);  // A: +staging/vmcnt (no reads)
  }

  // 1) casts to bf16
  {
    int n4 = SB * HDIM / 4;
    cast_bf16_kernel<<<(n4 + 255) / 256, 256, 0, stream>>>(
        (const float4*)X, (ushort4*)Xbf, n4);
    n4 = HDIM * HDIM / 4;
    cast_bf16_kernel<<<(n4 + 255) / 256, 256, 0, stream>>>(
        (const float4*)gw1, (ushort4*)gw1bf, n4);
  }

  // 2) zero colsum accumulator (ws is poisoned before each call)
  hipMemsetAsync(colsum, 0, HDIM * sizeof(float), stream);

  // 3) gate GEMM -> relu -> column sums  (M=8192, N=1024, K=1024)
  gemm8p<0, 128><<<dim3(HDIM / 128, SB / 256), 512, 98304, stream>>>(
      Xbf, gw1bf, gb1, colsum, SB, HDIM, HDIM);

  // 4) lambda
  lam_kernel<<<1, 256, 0, stream>>>(colsum, gw2, gb2, lam);

  // 5) merge weights + biases
  {
    int n4 = FDIM * HDIM / 4;
    merge_w_kernel<<<(n4 + 255) / 256, 256, 0, stream>>>(
        (const float4*)bw1, (const float4*)tw1, lam, (ushort4*)w1m, n4);
    merge_w_kernel<<<(n4 + 255) / 256, 256, 0, stream>>>(
        (const float4*)bw2, (const float4*)tw2, lam, (ushort4*)w2m, n4);
    merge_b_kernel<<<(FDIM + 255) / 256, 256, 0, stream>>>(bb1, tb1, lam, b1m, FDIM);
    merge_b_kernel<<<(HDIM + 255) / 256, 256, 0, stream>>>(bb2, tb2, lam, b2m, HDIM);
  }

  // 6) h = relu(X @ w1m^T + b1m)   (M=8192, N=4096, K=1024), bf16 out
  gemm8p<1, 256><<<dim3(FDIM / 256, SB / 256), 512, 131072, stream>>>(
      Xbf, w1m, b1m, hbuf, SB, FDIM, HDIM);

  // 7) out = h @ w2m^T + b2m       (M=8192, N=1024, K=4096), fp32 out
  gemm8p<2, 128><<<dim3(HDIM / 128, SB / 256), 512, 98304, stream>>>(
      hbuf, w2m, b2m, out, SB, HDIM, FDIM);
}

// Round 6
// 561.110 us; speedup vs baseline: 1.8890x; 1.8890x over previous
//
#include <hip/hip_runtime.h>
#include <hip/hip_bf16.h>
#include <stdint.h>
#include <type_traits>

// Problem constants (S=2048, B=4, H=1024, F=4096, E=8)
#define SB   8192
#define HDIM 1024
#define FDIM 4096
#define EDIM 8

typedef __bf16 bf16x8 __attribute__((ext_vector_type(8)));
typedef float  f32x4  __attribute__((ext_vector_type(4)));

__device__ __forceinline__ void g2l16(const void* g, void* l) {
  __builtin_amdgcn_global_load_lds(
      (const __attribute__((address_space(1))) uint32_t*)g,
      (__attribute__((address_space(3))) uint32_t*)l, 16, 0, 0);
}

__device__ __forceinline__ unsigned short f2bf(float f) {
  __hip_bfloat16 b = __float2bfloat16(f);
  return *reinterpret_cast<unsigned short*>(&b);
}

// inline-asm ds_read_b128 with compile-time offset immediate.
template <int IMM>
__device__ __forceinline__ bf16x8 lds_rd128(int addr) {
  static_assert(IMM >= 0 && IMM < 65536, "ds offset");
  bf16x8 r;
  asm volatile("ds_read_b128 %0, %1 offset:%2" : "=v"(r) : "v"(addr), "n"(IMM));
  return r;
}

// ---------------- cast fp32 -> bf16 (vectorized) ----------------
__global__ void cast_bf16_kernel(const float4* __restrict__ in,
                                 ushort4* __restrict__ out, int n4) {
  int i = blockIdx.x * blockDim.x + threadIdx.x;
  if (i < n4) {
    float4 v = in[i];
    ushort4 o;
    o.x = f2bf(v.x); o.y = f2bf(v.y); o.z = f2bf(v.z); o.w = f2bf(v.w);
    out[i] = o;
  }
}

// ---------------- lambda: lam[e] = gb2[e] + dot(colsum, gw2[e,:]) / 8192 ----
__global__ void lam_kernel(const float* __restrict__ colsum,
                           const float* __restrict__ gw2,
                           const float* __restrict__ gb2,
                           float* __restrict__ lam) {
  __shared__ float red[256];
  const int tid = threadIdx.x;
  for (int e = 0; e < EDIM; ++e) {
    float p = 0.f;
    for (int h = tid; h < HDIM; h += 256) p += colsum[h] * gw2[e * HDIM + h];
    red[tid] = p;
    __syncthreads();
    for (int s = 128; s > 0; s >>= 1) {
      if (tid < s) red[tid] += red[tid + s];
      __syncthreads();
    }
    if (tid == 0) lam[e] = gb2[e] + red[0] * (1.f / 8192.f);
    __syncthreads();
  }
}

// ---------------- merge weights: out_bf16 = base + sum_e lam[e]*tv[e] ------
__global__ void merge_w_kernel(const float4* __restrict__ base,
                               const float4* __restrict__ tv,
                               const float* __restrict__ lam,
                               ushort4* __restrict__ outw, int n4) {
  int i = blockIdx.x * blockDim.x + threadIdx.x;
  if (i >= n4) return;
  float l[EDIM];
#pragma unroll
  for (int e = 0; e < EDIM; ++e) l[e] = lam[e];
  float4 v = base[i];
#pragma unroll
  for (int e = 0; e < EDIM; ++e) {
    float4 t = tv[(size_t)e * n4 + i];
    v.x += l[e] * t.x; v.y += l[e] * t.y; v.z += l[e] * t.z; v.w += l[e] * t.w;
  }
  ushort4 o;
  o.x = f2bf(v.x); o.y = f2bf(v.y); o.z = f2bf(v.z); o.w = f2bf(v.w);
  outw[i] = o;
}

// ---------------- merge biases (fp32 out, tiny) ----------------------------
__global__ void merge_b_kernel(const float* __restrict__ base,
                               const float* __restrict__ tv,
                               const float* __restrict__ lam,
                               float* __restrict__ outb, int n) {
  int i = blockIdx.x * blockDim.x + threadIdx.x;
  if (i >= n) return;
  float v = base[i];
#pragma unroll
  for (int e = 0; e < EDIM; ++e) v += lam[e] * tv[(size_t)e * n + i];
  outb[i] = v;
}

// ---------------------------------------------------------------------------
// gemm2p: co-residency-first pipelined MFMA bt-GEMM.  C[M,N] = A[M,K]*B[N,K]^T
// R5 diag verdict: the 8-phase 128KB-LDS design exposes ~460cy/phase of bare
// barrier overhead (ABL=0: 975cy vs 512cy MFMA floor) because only ONE block
// fits per CU; the read+stage combination adds ~675cy more.  Fix = occupancy:
//   BM x 128 tile, BK=32, 512 thr (8 waves 2Mx4N), per-wave BM/2 x 32.
//   3-deep LDS ring (BM=256: 72KB, BM=128: 48KB) -> 2 blocks/CU, 4 waves/SIMD
//   -> the other block's waves hide every barrier/vmcnt stall.
//   Counted prefetch: iter j stages tile j+2; tail waits vmcnt(LPI) = only
//   loads issued >=1 full iteration earlier must be complete.  One barrier
//   per iter.  Races (traced): ring written at iter j was last read at iter
//   j-1 whose reads are lgkm-drained before its end barrier; reads at iter j
//   use loads vmcnt-confirmed at end of iter j-1.
// LDS layout: A rings at ring*BM*64 bytes ([row][32] 64B rows, XOR-swizzled
// content via pre-swizzled global source; rule 21); B rings at 3*BM*64 +
// ring*8192.  All ds_read offsets are 16-bit immediates off 2 base VGPRs.
// MODE 0: bias+relu, column-sum atomicAdd.  1: bias+relu bf16.  2: bias fp32.
template <int MODE, int BM>
__global__ void __launch_bounds__(512, 4)
gemm2p(const ushort* __restrict__ A, const ushort* __restrict__ B,
       const float* __restrict__ bias, void* __restrict__ Cout,
       int M, int N, int K) {
  constexpr int MI   = BM / 32;        // A frags per wave (8 or 4)
  constexpr int LPI  = BM / 128 + 1;   // global_load_lds per iter (3 or 2)
  constexpr int AR_E = BM * 32;        // A region elems (chunk=4096 elems)
  constexpr int ARB  = BM * 64;        // A region bytes
  extern __shared__ __align__(16) ushort smem[];
  (void)M;

  const int tid  = threadIdx.x;
  const int lane = tid & 63;
  const int wave = tid >> 6;
  const int wm = wave >> 2, wn = wave & 3;
  const int lr = lane & 15, lq = lane >> 4;

  // XCD-aware swizzle (gridDim.y % 8 == 0)
  const int bid = blockIdx.y * gridDim.x + blockIdx.x;
  const int gx  = gridDim.x;
  const int Yc  = gridDim.y >> 3;
  const int xcd = bid & 7;
  const int tt  = bid >> 3;
  const int tq  = tt / gx;
  const int ty  = xcd * Yc + tq;
  const int tx  = tt - tq * gx;
  const int m0 = ty * BM, n0 = tx * 128;

  const int NT = K >> 5;  // BK=32 steps; >= 32 for all our shapes

  // ---- LDS read bases (swizzle term lane-constant: row steps of 16)
  const uint32_t smemBase =
      (uint32_t)(uintptr_t)(__attribute__((address_space(3))) ushort*)smem;
  const int rowAl = wm * (BM / 2) + lr;
  const int vA = (int)smemBase + rowAl * 64 + ((lq ^ ((rowAl >> 1) & 3)) << 4);
  const int rowBl = wn * 32 + lr;
  const int vB = (int)smemBase + 3 * ARB + rowBl * 64 +
                 ((lq ^ ((rowBl >> 1) & 3)) << 4);

  // ---- staging pointers (global src pre-swizzled, LDS dest lane-linear).
  const int rr = tid >> 2;
  const int colS = ((tid & 3) ^ ((rr >> 1) & 3)) * 8;
  const ushort* gA0p = A + (size_t)(m0 + rr) * K + colS;
  const ushort* gA1p = gA0p + (size_t)128 * K;   // BM==256 only
  const ushort* gB0p = B + (size_t)(n0 + rr) * K + colS;
  ushort* lds0 = smem + tid * 8;

  f32x4 acc[MI][2];
#pragma unroll
  for (int i = 0; i < MI; ++i)
#pragma unroll
    for (int n = 0; n < 2; ++n)
#pragma unroll
      for (int r = 0; r < 4; ++r) acc[i][n][r] = 0.f;

  // stage one K-step tile into ring r
  auto stage = [&](int r, int kt) {
    const int kk = kt * 32;
    ushort* la = lds0 + r * AR_E;
    g2l16(gA0p + kk, la);
    if constexpr (BM == 256) g2l16(gA1p + kk, la + 4096);
    g2l16(gB0p + kk, lds0 + 3 * AR_E + r * 4096);
  };

  // ---- prologue: tiles 0,1 into rings 0,1; ring0 confirmed
  stage(0, 0);
  stage(1, 1);
  __builtin_amdgcn_sched_barrier(0);
  asm volatile("s_waitcnt vmcnt(%0)" ::"n"(LPI));
  __builtin_amdgcn_s_barrier();
  __builtin_amdgcn_sched_barrier(0);

  int ring = 0, rs = 2;
  for (int j = 0; j < NT; ++j) {
    const bool st = (j + 2) < NT;
    if (st) stage(rs, j + 2);
    __builtin_amdgcn_sched_barrier(0);
    // fragment reads from ring (asm, immediate offsets off runtime ring base)
    const int aB = vA + ring * ARB;
    const int bB = vB + ring * 8192;
    bf16x8 bfr[2], afr[MI];
    bfr[0] = lds_rd128<0>(bB);
    bfr[1] = lds_rd128<1024>(bB);
    afr[0] = lds_rd128<0>(aB);
    afr[1] = lds_rd128<1024>(aB);
    afr[2] = lds_rd128<2048>(aB);
    afr[3] = lds_rd128<3072>(aB);
    if constexpr (MI == 8) {
      afr[4] = lds_rd128<4096>(aB);
      afr[5] = lds_rd128<5120>(aB);
      afr[6] = lds_rd128<6144>(aB);
      afr[7] = lds_rd128<7168>(aB);
    }
    asm volatile("s_waitcnt lgkmcnt(0)");
    __builtin_amdgcn_sched_barrier(0);
    __builtin_amdgcn_s_setprio(1);
#pragma unroll
    for (int i = 0; i < MI; ++i)
#pragma unroll
      for (int n = 0; n < 2; ++n)
        acc[i][n] = __builtin_amdgcn_mfma_f32_16x16x32_bf16(
            afr[i], bfr[n], acc[i][n], 0, 0, 0);
    __builtin_amdgcn_s_setprio(0);
    __builtin_amdgcn_sched_barrier(0);
    if (st) {
      asm volatile("s_waitcnt vmcnt(%0)" ::"n"(LPI));  // tile j+1 resident
    } else if (j + 1 < NT) {
      asm volatile("s_waitcnt vmcnt(0)");              // final tile resident
    }
    __builtin_amdgcn_s_barrier();
    __builtin_amdgcn_sched_barrier(0);
    ring = (ring == 2) ? 0 : ring + 1;
    rs   = (rs == 2) ? 0 : rs + 1;
  }

  // ---- epilogue.  C/D layout (verified m89/m91): col=ni*16+lr, row=lq*4+r.
  const int gm = m0 + wm * (BM / 2);
  const int gn = n0 + wn * 32;
  if constexpr (MODE == 0) {
    float* colsum = (float*)Cout;
#pragma unroll
    for (int ni = 0; ni < 2; ++ni) {
      const int col = gn + ni * 16 + lr;
      const float bv = bias[col];
      float p = 0.f;
#pragma unroll
      for (int mi = 0; mi < MI; ++mi)
#pragma unroll
        for (int r = 0; r < 4; ++r) {
          float v = acc[mi][ni][r] + bv;
          p += v > 0.f ? v : 0.f;
        }
      p += __shfl_xor(p, 16);
      p += __shfl_xor(p, 32);
      if (lq == 0) atomicAdd(&colsum[col], p);
    }
  } else if constexpr (MODE == 1) {
    __hip_bfloat16* C = (__hip_bfloat16*)Cout;
#pragma unroll
    for (int ni = 0; ni < 2; ++ni) {
      const int col = gn + ni * 16 + lr;
      const float bv = bias[col];
#pragma unroll
      for (int mi = 0; mi < MI; ++mi)
#pragma unroll
        for (int r = 0; r < 4; ++r) {
          const int row = gm + mi * 16 + lq * 4 + r;
          float v = acc[mi][ni][r] + bv;
          v = v > 0.f ? v : 0.f;
          C[(size_t)row * N + col] = __float2bfloat16(v);
        }
    }
  } else {
    float* C = (float*)Cout;
#pragma unroll
    for (int ni = 0; ni < 2; ++ni) {
      const int col = gn + ni * 16 + lr;
      const float bv = bias[col];
#pragma unroll
      for (int mi = 0; mi < MI; ++mi)
#pragma unroll
        for (int r = 0; r < 4; ++r) {
          const int row = gm + mi * 16 + lq * 4 + r;
          C[(size_t)row * N + col] = acc[mi][ni][r] + bv;
        }
    }
  }
}

// ---------------------------------------------------------------------------
extern "C" void kernel_launch(void* const* d_in, const int* in_sizes, int n_in,
                              void* d_out, int out_size, void* d_ws, size_t ws_size,
                              hipStream_t stream) {
  const float* X   = (const float*)d_in[0];   // [S,B,H]
  const float* gw1 = (const float*)d_in[1];   // [H,H]
  const float* gb1 = (const float*)d_in[2];   // [H]
  const float* gw2 = (const float*)d_in[3];   // [E,H]
  const float* gb2 = (const float*)d_in[4];   // [E]
  const float* bw1 = (const float*)d_in[5];   // [F,H]
  const float* bb1 = (const float*)d_in[6];   // [F]
  const float* bw2 = (const float*)d_in[7];   // [H,F]
  const float* bb2 = (const float*)d_in[8];   // [H]
  const float* tw1 = (const float*)d_in[9];   // [E,F,H]
  const float* tb1 = (const float*)d_in[10];  // [E,F]
  const float* tw2 = (const float*)d_in[11];  // [E,H,F]
  const float* tb2 = (const float*)d_in[12];  // [E,H]
  float* out = (float*)d_out;                 // [S,B,H]

  // one-time: allow >64KB dynamic LDS where needed
  static bool s_attr = false;
  if (!s_attr) {
    (void)hipFuncSetAttribute(reinterpret_cast<const void*>(gemm2p<0, 128>),
                              hipFuncAttributeMaxDynamicSharedMemorySize, 49152);
    (void)hipFuncSetAttribute(reinterpret_cast<const void*>(gemm2p<2, 128>),
                              hipFuncAttributeMaxDynamicSharedMemorySize, 49152);
    (void)hipFuncSetAttribute(reinterpret_cast<const void*>(gemm2p<1, 256>),
                              hipFuncAttributeMaxDynamicSharedMemorySize, 73728);
    s_attr = true;
  }

  // workspace carve (256B aligned)
  size_t off = 0;
  auto carve = [&](size_t bytes) -> void* {
    void* p = (char*)d_ws + off;
    off += (bytes + 255) & ~(size_t)255;
    return p;
  };
  ushort* Xbf   = (ushort*)carve((size_t)SB * HDIM * 2);     // X in bf16
  ushort* gw1bf = (ushort*)carve((size_t)HDIM * HDIM * 2);   // gate w1 bf16
  ushort* w1m   = (ushort*)carve((size_t)FDIM * HDIM * 2);   // merged w1 bf16
  ushort* w2m   = (ushort*)carve((size_t)HDIM * FDIM * 2);   // merged w2 bf16
  ushort* hbuf  = (ushort*)carve((size_t)SB * FDIM * 2);     // h bf16
  float* b1m    = (float*)carve(FDIM * 4);
  float* b2m    = (float*)carve(HDIM * 4);
  float* colsum = (float*)carve(HDIM * 4);
  float* lam    = (float*)carve(EDIM * 4);

  // 1) casts to bf16
  {
    int n4 = SB * HDIM / 4;
    cast_bf16_kernel<<<(n4 + 255) / 256, 256, 0, stream>>>(
        (const float4*)X, (ushort4*)Xbf, n4);
    n4 = HDIM * HDIM / 4;
    cast_bf16_kernel<<<(n4 + 255) / 256, 256, 0, stream>>>(
        (const float4*)gw1, (ushort4*)gw1bf, n4);
  }

  // 2) zero colsum accumulator (ws is poisoned before each call)
  hipMemsetAsync(colsum, 0, HDIM * sizeof(float), stream);

  // 3) gate GEMM -> relu -> column sums  (M=8192, N=1024, K=1024), 128x128
  gemm2p<0, 128><<<dim3(HDIM / 128, SB / 128), 512, 49152, stream>>>(
      Xbf, gw1bf, gb1, colsum, SB, HDIM, HDIM);

  // 4) lambda
  lam_kernel<<<1, 256, 0, stream>>>(colsum, gw2, gb2, lam);

  // 5) merge weights + biases
  {
    int n4 = FDIM * HDIM / 4;
    merge_w_kernel<<<(n4 + 255) / 256, 256, 0, stream>>>(
        (const float4*)bw1, (const float4*)tw1, lam, (ushort4*)w1m, n4);
    merge_w_kernel<<<(n4 + 255) / 256, 256, 0, stream>>>(
        (const float4*)bw2, (const float4*)tw2, lam, (ushort4*)w2m, n4);
    merge_b_kernel<<<(FDIM + 255) / 256, 256, 0, stream>>>(bb1, tb1, lam, b1m, FDIM);
    merge_b_kernel<<<(HDIM + 255) / 256, 256, 0, stream>>>(bb2, tb2, lam, b2m, HDIM);
  }

  // 6) h = relu(X @ w1m^T + b1m)   (M=8192, N=4096, K=1024), bf16 out, 256x128
  gemm2p<1, 256><<<dim3(FDIM / 128, SB / 256), 512, 73728, stream>>>(
      Xbf, w1m, b1m, hbuf, SB, FDIM, HDIM);

  // 7) out = h @ w2m^T + b2m       (M=8192, N=1024, K=4096), fp32 out, 128x128
  gemm2p<2, 128><<<dim3(HDIM / 128, SB / 128), 512, 49152, stream>>>(
      hbuf, w2m, b2m, out, SB, HDIM, FDIM);
}

// Round 7
// 552.718 us; speedup vs baseline: 1.9176x; 1.0152x over previous
//
#include <hip/hip_runtime.h>
#include <hip/hip_bf16.h>
#include <stdint.h>
#include <type_traits>

// Problem constants (S=2048, B=4, H=1024, F=4096, E=8)
#define SB   8192
#define HDIM 1024
#define FDIM 4096
#define EDIM 8

typedef __bf16 bf16x8 __attribute__((ext_vector_type(8)));
typedef float  f32x4  __attribute__((ext_vector_type(4)));

__device__ __forceinline__ void g2l16(const void* g, void* l) {
  __builtin_amdgcn_global_load_lds(
      (const __attribute__((address_space(1))) uint32_t*)g,
      (__attribute__((address_space(3))) uint32_t*)l, 16, 0, 0);
}

__device__ __forceinline__ unsigned short f2bf(float f) {
  __hip_bfloat16 b = __float2bfloat16(f);
  return *reinterpret_cast<unsigned short*>(&b);
}

// inline-asm ds_read_b128 with compile-time offset immediate.
template <int IMM>
__device__ __forceinline__ bf16x8 lds_rd128(int addr) {
  static_assert(IMM >= 0 && IMM < 65536, "ds offset");
  bf16x8 r;
  asm volatile("ds_read_b128 %0, %1 offset:%2" : "=v"(r) : "v"(addr), "n"(IMM));
  return r;
}

// ---------------- prep: cast X + gw1 to bf16, zero colsum (1 launch) -------
__global__ void prep_kernel(const float4* __restrict__ X,
                            ushort4* __restrict__ Xbf,
                            const float4* __restrict__ gw1,
                            ushort4* __restrict__ gw1bf,
                            float* __restrict__ colsum) {
  const int i = blockIdx.x * blockDim.x + threadIdx.x;
  constexpr int n4x = SB * HDIM / 4;
  constexpr int n4g = HDIM * HDIM / 4;
  if (i < HDIM) colsum[i] = 0.f;
  if (i < n4x) {
    float4 v = X[i];
    ushort4 o;
    o.x = f2bf(v.x); o.y = f2bf(v.y); o.z = f2bf(v.z); o.w = f2bf(v.w);
    Xbf[i] = o;
  } else if (i < n4x + n4g) {
    const int j = i - n4x;
    float4 v = gw1[j];
    ushort4 o;
    o.x = f2bf(v.x); o.y = f2bf(v.y); o.z = f2bf(v.z); o.w = f2bf(v.w);
    gw1bf[j] = o;
  }
}

// ---------------- lambda: lam[e] = gb2[e] + dot(colsum, gw2[e,:]) / 8192 ----
__global__ void lam_kernel(const float* __restrict__ colsum,
                           const float* __restrict__ gw2,
                           const float* __restrict__ gb2,
                           float* __restrict__ lam) {
  __shared__ float red[256];
  const int tid = threadIdx.x;
  for (int e = 0; e < EDIM; ++e) {
    float p = 0.f;
    for (int h = tid; h < HDIM; h += 256) p += colsum[h] * gw2[e * HDIM + h];
    red[tid] = p;
    __syncthreads();
    for (int s = 128; s > 0; s >>= 1) {
      if (tid < s) red[tid] += red[tid + s];
      __syncthreads();
    }
    if (tid == 0) lam[e] = gb2[e] + red[0] * (1.f / 8192.f);
    __syncthreads();
  }
}

// ---------------- merge weights: out_bf16 = base + sum_e lam[e]*tv[e] ------
__global__ void merge_w_kernel(const float4* __restrict__ base,
                               const float4* __restrict__ tv,
                               const float* __restrict__ lam,
                               ushort4* __restrict__ outw, int n4) {
  int i = blockIdx.x * blockDim.x + threadIdx.x;
  if (i >= n4) return;
  float l[EDIM];
#pragma unroll
  for (int e = 0; e < EDIM; ++e) l[e] = lam[e];
  float4 v = base[i];
#pragma unroll
  for (int e = 0; e < EDIM; ++e) {
    float4 t = tv[(size_t)e * n4 + i];
    v.x += l[e] * t.x; v.y += l[e] * t.y; v.z += l[e] * t.z; v.w += l[e] * t.w;
  }
  ushort4 o;
  o.x = f2bf(v.x); o.y = f2bf(v.y); o.z = f2bf(v.z); o.w = f2bf(v.w);
  outw[i] = o;
}

// ---------------- merge both biases in one launch --------------------------
__global__ void merge_b_both(const float* __restrict__ bb1,
                             const float* __restrict__ tb1,
                             float* __restrict__ b1m,
                             const float* __restrict__ bb2,
                             const float* __restrict__ tb2,
                             float* __restrict__ b2m,
                             const float* __restrict__ lam) {
  const int i = blockIdx.x * blockDim.x + threadIdx.x;
  float l[EDIM];
#pragma unroll
  for (int e = 0; e < EDIM; ++e) l[e] = lam[e];
  if (i < FDIM) {
    float v = bb1[i];
#pragma unroll
    for (int e = 0; e < EDIM; ++e) v += l[e] * tb1[e * FDIM + i];
    b1m[i] = v;
  }
  const int j = i - FDIM;
  if (j >= 0 && j < HDIM) {
    float v = bb2[j];
#pragma unroll
    for (int e = 0; e < EDIM; ++e) v += l[e] * tb2[e * HDIM + j];
    b2m[j] = v;
  }
}

// ---------------------------------------------------------------------------
// gemm2p: co-residency pipelined MFMA bt-GEMM.  C[M,N] = A[M,K]*B[N,K]^T
// R7 changes (from R6 post-mortem):
//  * BM=128: per-iter wall ~800cy < HBM-miss latency ~900cy, so the vmcnt
//    confirm of tile j+1 (issued 1 iter earlier) was structurally exposed.
//    Fix: RING=4, stage 3 ahead -> confirm lead ~1600cy.  LDS 64KB, still
//    2 blocks/CU.
//  * BM=256: wave layout 4Mx2N (was 2Mx4N) -> per-wave 64x64, MI=4, NF=4:
//    8 ds_reads/iter (was 10) for the same 16 MFMA.  RING=3 (LDS cap, 72KB);
//    per-iter wall ~3200cy >> 900cy so 2-ahead confirm is fine there.
// Invariants carried from R6 (harness-verified): XOR-swizzled content via
// pre-swizzled global source + lane-linear LDS dest (rule 21); asm ds_read
// with imm offsets; lgkm-drain before end barrier; slot written at iter j was
// read at iter j-1 and drained before its end barrier.
// MODE 0: bias+relu colsum atomicAdd.  1: bias+relu bf16.  2: bias fp32.
template <int MODE, int BM>
__global__ void __launch_bounds__(512, 4)
gemm2p(const ushort* __restrict__ A, const ushort* __restrict__ B,
       const float* __restrict__ bias, void* __restrict__ Cout,
       int M, int N, int K) {
  constexpr int RING = (BM == 256) ? 3 : 4;
  constexpr int LPI  = (BM == 256) ? 3 : 2;   // global_load_lds per tile
  constexpr int MI   = 4;                      // A frags per wave
  constexpr int NF   = (BM == 256) ? 4 : 2;    // B frags per wave
  constexpr int AR_E = BM * 32;                // A ring elems
  constexpr int ARB  = BM * 64;                // A ring bytes
  extern __shared__ __align__(16) ushort smem[];
  (void)M;

  const int tid  = threadIdx.x;
  const int lane = tid & 63;
  const int wave = tid >> 6;
  const int wm = (BM == 256) ? (wave >> 1) : (wave >> 2);
  const int wn = (BM == 256) ? (wave & 1) : (wave & 3);
  const int lr = lane & 15, lq = lane >> 4;

  // XCD-aware swizzle (gridDim.y % 8 == 0)
  const int bid = blockIdx.y * gridDim.x + blockIdx.x;
  const int gx  = gridDim.x;
  const int Yc  = gridDim.y >> 3;
  const int xcd = bid & 7;
  const int tt  = bid >> 3;
  const int tq  = tt / gx;
  const int ty  = xcd * Yc + tq;
  const int tx  = tt - tq * gx;
  const int m0 = ty * BM, n0 = tx * 128;

  const int NT = K >> 5;  // BK=32 steps; >= 32 for all our shapes

  // ---- LDS read bases (swizzle term lane-constant: row steps of 16)
  const uint32_t smemBase =
      (uint32_t)(uintptr_t)(__attribute__((address_space(3))) ushort*)smem;
  const int rowAl = wm * 64 + lr;
  const int vA = (int)smemBase + rowAl * 64 + ((lq ^ ((rowAl >> 1) & 3)) << 4);
  const int rowBl = wn * (NF * 16) + lr;
  const int vB = (int)smemBase + RING * ARB + rowBl * 64 +
                 ((lq ^ ((rowBl >> 1) & 3)) << 4);

  // ---- staging pointers (global src pre-swizzled, LDS dest lane-linear).
  const int rr = tid >> 2;
  const int colS = ((tid & 3) ^ ((rr >> 1) & 3)) * 8;
  const ushort* gA0p = A + (size_t)(m0 + rr) * K + colS;
  const ushort* gA1p = gA0p + (size_t)128 * K;   // BM==256 only
  const ushort* gB0p = B + (size_t)(n0 + rr) * K + colS;
  ushort* lds0 = smem + tid * 8;

  f32x4 acc[MI][NF];
#pragma unroll
  for (int i = 0; i < MI; ++i)
#pragma unroll
    for (int n = 0; n < NF; ++n)
#pragma unroll
      for (int r = 0; r < 4; ++r) acc[i][n][r] = 0.f;

  // stage one K-step tile into ring slot
  auto stage = [&](int slot, int kt) {
    const int kk = kt * 32;
    ushort* la = lds0 + slot * AR_E;
    g2l16(gA0p + kk, la);
    if constexpr (BM == 256) g2l16(gA1p + kk, la + 4096);
    g2l16(gB0p + kk, lds0 + RING * AR_E + slot * 4096);
  };

  // ---- prologue: tiles 0..RING-2; confirm tile 0
#pragma unroll
  for (int r = 0; r < RING - 1; ++r) stage(r, r);
  __builtin_amdgcn_sched_barrier(0);
  if constexpr (RING == 3) asm volatile("s_waitcnt vmcnt(3)");
  else                     asm volatile("s_waitcnt vmcnt(4)");
  __builtin_amdgcn_s_barrier();
  __builtin_amdgcn_sched_barrier(0);

  int rdSlot = 0, stSlot = RING - 1, stTile = RING - 1;
  for (int j = 0; j < NT; ++j) {
    if (stTile < NT) stage(stSlot, stTile);
    __builtin_amdgcn_sched_barrier(0);
    // fragment reads (asm, imm offsets off runtime ring base)
    const int aB = vA + rdSlot * ARB;
    const int bB = vB + rdSlot * 8192;
    bf16x8 bfr[NF], afr[MI];
    bfr[0] = lds_rd128<0>(bB);
    bfr[1] = lds_rd128<1024>(bB);
    if constexpr (NF == 4) {
      bfr[2] = lds_rd128<2048>(bB);
      bfr[3] = lds_rd128<3072>(bB);
    }
    afr[0] = lds_rd128<0>(aB);
    afr[1] = lds_rd128<1024>(aB);
    afr[2] = lds_rd128<2048>(aB);
    afr[3] = lds_rd128<3072>(aB);
    asm volatile("s_waitcnt lgkmcnt(0)");
    __builtin_amdgcn_sched_barrier(0);
    __builtin_amdgcn_s_setprio(1);
#pragma unroll
    for (int i = 0; i < MI; ++i)
#pragma unroll
      for (int n = 0; n < NF; ++n)
        acc[i][n] = __builtin_amdgcn_mfma_f32_16x16x32_bf16(
            afr[i], bfr[n], acc[i][n], 0, 0, 0);
    __builtin_amdgcn_s_setprio(0);
    __builtin_amdgcn_sched_barrier(0);
    // confirm tile j+1 resident (counted; issued >= RING-2 iters earlier)
    if (j + 1 < NT) {
      const int ls = stTile < NT ? stTile : NT - 1;
      const int ahead = ls - (j + 1);
      if constexpr (RING == 3) {
        if (ahead >= 1) asm volatile("s_waitcnt vmcnt(3)");
        else            asm volatile("s_waitcnt vmcnt(0)");
      } else {
        if (ahead >= 2)      asm volatile("s_waitcnt vmcnt(4)");
        else if (ahead == 1) asm volatile("s_waitcnt vmcnt(2)");
        else                 asm volatile("s_waitcnt vmcnt(0)");
      }
    }
    __builtin_amdgcn_s_barrier();
    __builtin_amdgcn_sched_barrier(0);
    rdSlot = (rdSlot + 1 == RING) ? 0 : rdSlot + 1;
    stSlot = (stSlot + 1 == RING) ? 0 : stSlot + 1;
    ++stTile;
  }

  // ---- epilogue.  C/D layout (verified m89/m91): col=ni*16+lr, row=lq*4+r.
  const int gm = m0 + wm * 64;
  const int gn = n0 + wn * (NF * 16);
  if constexpr (MODE == 0) {
    float* colsum = (float*)Cout;
#pragma unroll
    for (int ni = 0; ni < NF; ++ni) {
      const int col = gn + ni * 16 + lr;
      const float bv = bias[col];
      float p = 0.f;
#pragma unroll
      for (int mi = 0; mi < MI; ++mi)
#pragma unroll
        for (int r = 0; r < 4; ++r) {
          float v = acc[mi][ni][r] + bv;
          p += v > 0.f ? v : 0.f;
        }
      p += __shfl_xor(p, 16);
      p += __shfl_xor(p, 32);
      if (lq == 0) atomicAdd(&colsum[col], p);
    }
  } else if constexpr (MODE == 1) {
    __hip_bfloat16* C = (__hip_bfloat16*)Cout;
#pragma unroll
    for (int ni = 0; ni < NF; ++ni) {
      const int col = gn + ni * 16 + lr;
      const float bv = bias[col];
#pragma unroll
      for (int mi = 0; mi < MI; ++mi)
#pragma unroll
        for (int r = 0; r < 4; ++r) {
          const int row = gm + mi * 16 + lq * 4 + r;
          float v = acc[mi][ni][r] + bv;
          v = v > 0.f ? v : 0.f;
          C[(size_t)row * N + col] = __float2bfloat16(v);
        }
    }
  } else {
    float* C = (float*)Cout;
#pragma unroll
    for (int ni = 0; ni < NF; ++ni) {
      const int col = gn + ni * 16 + lr;
      const float bv = bias[col];
#pragma unroll
      for (int mi = 0; mi < MI; ++mi)
#pragma unroll
        for (int r = 0; r < 4; ++r) {
          const int row = gm + mi * 16 + lq * 4 + r;
          C[(size_t)row * N + col] = acc[mi][ni][r] + bv;
        }
    }
  }
}

// ---------------------------------------------------------------------------
extern "C" void kernel_launch(void* const* d_in, const int* in_sizes, int n_in,
                              void* d_out, int out_size, void* d_ws, size_t ws_size,
                              hipStream_t stream) {
  const float* X   = (const float*)d_in[0];   // [S,B,H]
  const float* gw1 = (const float*)d_in[1];   // [H,H]
  const float* gb1 = (const float*)d_in[2];   // [H]
  const float* gw2 = (const float*)d_in[3];   // [E,H]
  const float* gb2 = (const float*)d_in[4];   // [E]
  const float* bw1 = (const float*)d_in[5];   // [F,H]
  const float* bb1 = (const float*)d_in[6];   // [F]
  const float* bw2 = (const float*)d_in[7];   // [H,F]
  const float* bb2 = (const float*)d_in[8];   // [H]
  const float* tw1 = (const float*)d_in[9];   // [E,F,H]
  const float* tb1 = (const float*)d_in[10];  // [E,F]
  const float* tw2 = (const float*)d_in[11];  // [E,H,F]
  const float* tb2 = (const float*)d_in[12];  // [E,H]
  float* out = (float*)d_out;                 // [S,B,H]

  // one-time: allow >64KB dynamic LDS where needed
  static bool s_attr = false;
  if (!s_attr) {
    (void)hipFuncSetAttribute(reinterpret_cast<const void*>(gemm2p<0, 128>),
                              hipFuncAttributeMaxDynamicSharedMemorySize, 65536);
    (void)hipFuncSetAttribute(reinterpret_cast<const void*>(gemm2p<2, 128>),
                              hipFuncAttributeMaxDynamicSharedMemorySize, 65536);
    (void)hipFuncSetAttribute(reinterpret_cast<const void*>(gemm2p<1, 256>),
                              hipFuncAttributeMaxDynamicSharedMemorySize, 73728);
    s_attr = true;
  }

  // workspace carve (256B aligned)
  size_t off = 0;
  auto carve = [&](size_t bytes) -> void* {
    void* p = (char*)d_ws + off;
    off += (bytes + 255) & ~(size_t)255;
    return p;
  };
  ushort* Xbf   = (ushort*)carve((size_t)SB * HDIM * 2);     // X in bf16
  ushort* gw1bf = (ushort*)carve((size_t)HDIM * HDIM * 2);   // gate w1 bf16
  ushort* w1m   = (ushort*)carve((size_t)FDIM * HDIM * 2);   // merged w1 bf16
  ushort* w2m   = (ushort*)carve((size_t)HDIM * FDIM * 2);   // merged w2 bf16
  ushort* hbuf  = (ushort*)carve((size_t)SB * FDIM * 2);     // h bf16
  float* b1m    = (float*)carve(FDIM * 4);
  float* b2m    = (float*)carve(HDIM * 4);
  float* colsum = (float*)carve(HDIM * 4);
  float* lam    = (float*)carve(EDIM * 4);

  // 1) prep: cast X + gw1 to bf16, zero colsum (1 launch)
  {
    constexpr int n4tot = SB * HDIM / 4 + HDIM * HDIM / 4;
    prep_kernel<<<(n4tot + 255) / 256, 256, 0, stream>>>(
        (const float4*)X, (ushort4*)Xbf, (const float4*)gw1, (ushort4*)gw1bf,
        colsum);
  }

  // 2) gate GEMM -> relu -> column sums  (M=8192, N=1024, K=1024), 128x128
  gemm2p<0, 128><<<dim3(HDIM / 128, SB / 128), 512, 65536, stream>>>(
      Xbf, gw1bf, gb1, colsum, SB, HDIM, HDIM);

  // 3) lambda
  lam_kernel<<<1, 256, 0, stream>>>(colsum, gw2, gb2, lam);

  // 4) merge weights + biases
  {
    int n4 = FDIM * HDIM / 4;
    merge_w_kernel<<<(n4 + 255) / 256, 256, 0, stream>>>(
        (const float4*)bw1, (const float4*)tw1, lam, (ushort4*)w1m, n4);
    merge_w_kernel<<<(n4 + 255) / 256, 256, 0, stream>>>(
        (const float4*)bw2, (const float4*)tw2, lam, (ushort4*)w2m, n4);
    merge_b_both<<<(FDIM + HDIM + 255) / 256, 256, 0, stream>>>(
        bb1, tb1, b1m, bb2, tb2, b2m, lam);
  }

  // 5) h = relu(X @ w1m^T + b1m)   (M=8192, N=4096, K=1024), bf16 out, 256x128
  gemm2p<1, 256><<<dim3(FDIM / 128, SB / 256), 512, 73728, stream>>>(
      Xbf, w1m, b1m, hbuf, SB, FDIM, HDIM);

  // 6) out = h @ w2m^T + b2m       (M=8192, N=1024, K=4096), fp32 out, 128x128
  gemm2p<2, 128><<<dim3(HDIM / 128, SB / 128), 512, 65536, stream>>>(
      hbuf, w2m, b2m, out, SB, HDIM, FDIM);
}

// Round 8
// 549.875 us; speedup vs baseline: 1.9276x; 1.0052x over previous
//
#include <hip/hip_runtime.h>
#include <hip/hip_bf16.h>
#include <stdint.h>
#include <type_traits>

// Problem constants (S=2048, B=4, H=1024, F=4096, E=8)
#define SB   8192
#define HDIM 1024
#define FDIM 4096
#define EDIM 8

typedef __bf16 bf16x8 __attribute__((ext_vector_type(8)));
typedef float  f32x4  __attribute__((ext_vector_type(4)));

__device__ __forceinline__ void g2l16(const void* g, void* l) {
  __builtin_amdgcn_global_load_lds(
      (const __attribute__((address_space(1))) uint32_t*)g,
      (__attribute__((address_space(3))) uint32_t*)l, 16, 0, 0);
}

__device__ __forceinline__ unsigned short f2bf(float f) {
  __hip_bfloat16 b = __float2bfloat16(f);
  return *reinterpret_cast<unsigned short*>(&b);
}

// inline-asm ds_read_b128 with compile-time offset immediate.
template <int IMM>
__device__ __forceinline__ bf16x8 lds_rd128(int addr) {
  static_assert(IMM >= 0 && IMM < 65536, "ds offset");
  bf16x8 r;
  asm volatile("ds_read_b128 %0, %1 offset:%2" : "=v"(r) : "v"(addr), "n"(IMM));
  return r;
}

// ---------------- prep: cast X + gw1 to bf16, zero colsum (1 launch) -------
__global__ void prep_kernel(const float4* __restrict__ X,
                            ushort4* __restrict__ Xbf,
                            const float4* __restrict__ gw1,
                            ushort4* __restrict__ gw1bf,
                            float* __restrict__ colsum) {
  const int i = blockIdx.x * blockDim.x + threadIdx.x;
  constexpr int n4x = SB * HDIM / 4;
  constexpr int n4g = HDIM * HDIM / 4;
  if (i < HDIM) colsum[i] = 0.f;
  if (i < n4x) {
    float4 v = X[i];
    ushort4 o;
    o.x = f2bf(v.x); o.y = f2bf(v.y); o.z = f2bf(v.z); o.w = f2bf(v.w);
    Xbf[i] = o;
  } else if (i < n4x + n4g) {
    const int j = i - n4x;
    float4 v = gw1[j];
    ushort4 o;
    o.x = f2bf(v.x); o.y = f2bf(v.y); o.z = f2bf(v.z); o.w = f2bf(v.w);
    gw1bf[j] = o;
  }
}

// ---------------- lambda: lam[e] = gb2[e] + dot(colsum, gw2[e,:]) / 8192 ----
__global__ void lam_kernel(const float* __restrict__ colsum,
                           const float* __restrict__ gw2,
                           const float* __restrict__ gb2,
                           float* __restrict__ lam) {
  __shared__ float red[256];
  const int tid = threadIdx.x;
  for (int e = 0; e < EDIM; ++e) {
    float p = 0.f;
    for (int h = tid; h < HDIM; h += 256) p += colsum[h] * gw2[e * HDIM + h];
    red[tid] = p;
    __syncthreads();
    for (int s = 128; s > 0; s >>= 1) {
      if (tid < s) red[tid] += red[tid + s];
      __syncthreads();
    }
    if (tid == 0) lam[e] = gb2[e] + red[0] * (1.f / 8192.f);
    __syncthreads();
  }
}

// ---------------- merge weights: out_bf16 = base + sum_e lam[e]*tv[e] ------
__global__ void merge_w_kernel(const float4* __restrict__ base,
                               const float4* __restrict__ tv,
                               const float* __restrict__ lam,
                               ushort4* __restrict__ outw, int n4) {
  int i = blockIdx.x * blockDim.x + threadIdx.x;
  if (i >= n4) return;
  float l[EDIM];
#pragma unroll
  for (int e = 0; e < EDIM; ++e) l[e] = lam[e];
  float4 v = base[i];
#pragma unroll
  for (int e = 0; e < EDIM; ++e) {
    float4 t = tv[(size_t)e * n4 + i];
    v.x += l[e] * t.x; v.y += l[e] * t.y; v.z += l[e] * t.z; v.w += l[e] * t.w;
  }
  ushort4 o;
  o.x = f2bf(v.x); o.y = f2bf(v.y); o.z = f2bf(v.z); o.w = f2bf(v.w);
  outw[i] = o;
}

// ---------------- merge both biases in one launch --------------------------
__global__ void merge_b_both(const float* __restrict__ bb1,
                             const float* __restrict__ tb1,
                             float* __restrict__ b1m,
                             const float* __restrict__ bb2,
                             const float* __restrict__ tb2,
                             float* __restrict__ b2m,
                             const float* __restrict__ lam) {
  const int i = blockIdx.x * blockDim.x + threadIdx.x;
  float l[EDIM];
#pragma unroll
  for (int e = 0; e < EDIM; ++e) l[e] = lam[e];
  if (i < FDIM) {
    float v = bb1[i];
#pragma unroll
    for (int e = 0; e < EDIM; ++e) v += l[e] * tb1[e * FDIM + i];
    b1m[i] = v;
  }
  const int j = i - FDIM;
  if (j >= 0 && j < HDIM) {
    float v = bb2[j];
#pragma unroll
    for (int e = 0; e < EDIM; ++e) v += l[e] * tb2[e * HDIM + j];
    b2m[j] = v;
  }
}

// ---------------------------------------------------------------------------
// gemm2p: ring-buffer pipelined MFMA bt-GEMM.  C[M,N] = A[M,K]*B[N,K]^T
// R8 model (fits all R0-R7 data): window = max(MFMA, LDS-pipe) + exposure.
// The knob is fragment reuse: reads/MFMA = (MI+NI)/(MI*NI).  mi4ni2 (0.75)
// saturates the LDS read pipe (R7: 85us, window 1594cy = LDS 1280 + 300);
// mi4ni4 (0.5) is the only config that measured <85 (R7 GEMM6).  So all
// GEMMs now use 64x64 wave tiles (MI=NI=4):
//   * 512-thr (WR4xWC2) 256x128 tile, RING=3 (72KB, 2 blocks/CU) - GEMM6.
//   * 256-thr (WR2xWC2) 128x128 tile, RING=4 (64KB, 2 blocks/CU) - gate,G7.
// BK=32; iter j stages tile j+RING-1 into the slot read at iter j-1 (drained
// by lgkmcnt(0)+barrier there); confirm of tile j+1 waits vmcnt(ahead*LPI)
// counted, never 0 until the tail.  Swizzled content via pre-swizzled global
// source + lane-linear LDS dest (rule 21); asm ds_read imm offsets.
// MODE 0: bias+relu colsum atomicAdd.  1: bias+relu bf16.  2: bias fp32.
template <int MODE, int BM, int BN, int WR, int WC, int RING>
__global__ void __launch_bounds__(WR * WC * 64, 4)
gemm2p(const ushort* __restrict__ A, const ushort* __restrict__ B,
       const float* __restrict__ bias, void* __restrict__ Cout,
       int M, int N, int K) {
  constexpr int THREADS = WR * WC * 64;
  constexpr int MI = (BM / WR) / 16;
  constexpr int NI = (BN / WC) / 16;
  static_assert(MI == 4 && NI == 4, "64x64 wave tile expected");
  constexpr int RPU = THREADS / 4;        // rows per g2l16 unit
  constexpr int UA  = BM / RPU;           // A units per tile
  constexpr int UB  = BN / RPU;           // B units per tile
  constexpr int LPI = UA + UB;            // loads per tile
  constexpr int AR_E = BM * 32;           // A slot elems
  constexpr int BR_E = BN * 32;           // B slot elems
  constexpr int ASB  = BM * 64;           // A slot bytes
  constexpr int BSB  = BN * 64;           // B slot bytes
  extern __shared__ __align__(16) ushort smem[];
  (void)M;

  const int tid  = threadIdx.x;
  const int lane = tid & 63;
  const int wave = tid >> 6;
  const int wm = wave / WC, wn = wave % WC;
  const int lr = lane & 15, lq = lane >> 4;

  // XCD-aware swizzle (gridDim.y % 8 == 0)
  const int bid = blockIdx.y * gridDim.x + blockIdx.x;
  const int gx  = gridDim.x;
  const int Yc  = gridDim.y >> 3;
  const int xcd = bid & 7;
  const int tt  = bid >> 3;
  const int tq  = tt / gx;
  const int ty  = xcd * Yc + tq;
  const int tx  = tt - tq * gx;
  const int m0 = ty * BM, n0 = tx * BN;

  const int NT = K >> 5;  // BK=32 steps

  // ---- LDS read bases (swizzle term lane-constant: row steps of 16)
  const uint32_t smemBase =
      (uint32_t)(uintptr_t)(__attribute__((address_space(3))) ushort*)smem;
  const int rowAl = wm * (BM / WR) + lr;
  const int vA = (int)smemBase + rowAl * 64 + ((lq ^ ((rowAl >> 1) & 3)) << 4);
  const int rowBl = wn * (BN / WC) + lr;
  const int vB = (int)smemBase + RING * ASB + rowBl * 64 +
                 ((lq ^ ((rowBl >> 1) & 3)) << 4);

  // ---- staging pointers (global src pre-swizzled, LDS dest lane-linear).
  const int rr = tid >> 2;
  const int colS = ((tid & 3) ^ ((rr >> 1) & 3)) * 8;
  const ushort* gAp = A + (size_t)(m0 + rr) * K + colS;
  const ushort* gBp = B + (size_t)(n0 + rr) * K + colS;
  ushort* lds0 = smem + tid * 8;

  f32x4 acc[4][4];
#pragma unroll
  for (int i = 0; i < 4; ++i)
#pragma unroll
    for (int n = 0; n < 4; ++n)
#pragma unroll
      for (int r = 0; r < 4; ++r) acc[i][n][r] = 0.f;

  // stage one K-step tile into ring slot
  auto stage = [&](int slot, int kt) {
    const int kk = kt * 32;
#pragma unroll
    for (int u = 0; u < UA; ++u)
      g2l16(gAp + (size_t)u * RPU * K + kk, lds0 + slot * AR_E + u * RPU * 32);
#pragma unroll
    for (int u = 0; u < UB; ++u)
      g2l16(gBp + (size_t)u * RPU * K + kk,
            lds0 + RING * AR_E + slot * BR_E + u * RPU * 32);
  };

  // ---- prologue: tiles 0..RING-2; confirm tile 0
#pragma unroll
  for (int r = 0; r < RING - 1; ++r) stage(r, r);
  __builtin_amdgcn_sched_barrier(0);
  asm volatile("s_waitcnt vmcnt(%0)" ::"n"((RING - 2) * LPI));
  __builtin_amdgcn_s_barrier();
  __builtin_amdgcn_sched_barrier(0);

  int rdSlot = 0, stSlot = RING - 1, stTile = RING - 1;
  for (int j = 0; j < NT; ++j) {
    if (stTile < NT) stage(stSlot, stTile);
    __builtin_amdgcn_sched_barrier(0);
    // fragment reads (asm, imm offsets off runtime ring base)
    const int aB = vA + rdSlot * ASB;
    const int bB = vB + rdSlot * BSB;
    bf16x8 bfr[4], afr[4];
    bfr[0] = lds_rd128<0>(bB);
    bfr[1] = lds_rd128<1024>(bB);
    bfr[2] = lds_rd128<2048>(bB);
    bfr[3] = lds_rd128<3072>(bB);
    afr[0] = lds_rd128<0>(aB);
    afr[1] = lds_rd128<1024>(aB);
    afr[2] = lds_rd128<2048>(aB);
    afr[3] = lds_rd128<3072>(aB);
    asm volatile("s_waitcnt lgkmcnt(0)");
    __builtin_amdgcn_sched_barrier(0);
    __builtin_amdgcn_s_setprio(1);
#pragma unroll
    for (int i = 0; i < 4; ++i)
#pragma unroll
      for (int n = 0; n < 4; ++n)
        acc[i][n] = __builtin_amdgcn_mfma_f32_16x16x32_bf16(
            afr[i], bfr[n], acc[i][n], 0, 0, 0);
    __builtin_amdgcn_s_setprio(0);
    __builtin_amdgcn_sched_barrier(0);
    // confirm tile j+1 resident (counted; issued RING-2 iters earlier)
    if (j + 1 < NT) {
      const int ls = stTile < NT ? stTile : NT - 1;
      const int ahead = ls - (j + 1);
      if constexpr (RING == 3) {
        if (ahead >= 1) asm volatile("s_waitcnt vmcnt(%0)" ::"n"(LPI));
        else            asm volatile("s_waitcnt vmcnt(0)");
      } else {  // RING == 4
        if (ahead >= 2)      asm volatile("s_waitcnt vmcnt(%0)" ::"n"(2 * LPI));
        else if (ahead == 1) asm volatile("s_waitcnt vmcnt(%0)" ::"n"(LPI));
        else                 asm volatile("s_waitcnt vmcnt(0)");
      }
    }
    __builtin_amdgcn_s_barrier();
    __builtin_amdgcn_sched_barrier(0);
    rdSlot = (rdSlot + 1 == RING) ? 0 : rdSlot + 1;
    stSlot = (stSlot + 1 == RING) ? 0 : stSlot + 1;
    ++stTile;
  }

  // ---- epilogue.  C/D layout (verified m89/m91): col=ni*16+lr, row=lq*4+r.
  const int gm = m0 + wm * (BM / WR);
  const int gn = n0 + wn * (BN / WC);
  if constexpr (MODE == 0) {
    float* colsum = (float*)Cout;
#pragma unroll
    for (int ni = 0; ni < 4; ++ni) {
      const int col = gn + ni * 16 + lr;
      const float bv = bias[col];
      float p = 0.f;
#pragma unroll
      for (int mi = 0; mi < 4; ++mi)
#pragma unroll
        for (int r = 0; r < 4; ++r) {
          float v = acc[mi][ni][r] + bv;
          p += v > 0.f ? v : 0.f;
        }
      p += __shfl_xor(p, 16);
      p += __shfl_xor(p, 32);
      if (lq == 0) atomicAdd(&colsum[col], p);
    }
  } else if constexpr (MODE == 1) {
    __hip_bfloat16* C = (__hip_bfloat16*)Cout;
#pragma unroll
    for (int ni = 0; ni < 4; ++ni) {
      const int col = gn + ni * 16 + lr;
      const float bv = bias[col];
#pragma unroll
      for (int mi = 0; mi < 4; ++mi)
#pragma unroll
        for (int r = 0; r < 4; ++r) {
          const int row = gm + mi * 16 + lq * 4 + r;
          float v = acc[mi][ni][r] + bv;
          v = v > 0.f ? v : 0.f;
          C[(size_t)row * N + col] = __float2bfloat16(v);
        }
    }
  } else {
    float* C = (float*)Cout;
#pragma unroll
    for (int ni = 0; ni < 4; ++ni) {
      const int col = gn + ni * 16 + lr;
      const float bv = bias[col];
#pragma unroll
      for (int mi = 0; mi < 4; ++mi)
#pragma unroll
        for (int r = 0; r < 4; ++r) {
          const int row = gm + mi * 16 + lq * 4 + r;
          C[(size_t)row * N + col] = acc[mi][ni][r] + bv;
        }
    }
  }
}

// ---------------------------------------------------------------------------
extern "C" void kernel_launch(void* const* d_in, const int* in_sizes, int n_in,
                              void* d_out, int out_size, void* d_ws, size_t ws_size,
                              hipStream_t stream) {
  const float* X   = (const float*)d_in[0];   // [S,B,H]
  const float* gw1 = (const float*)d_in[1];   // [H,H]
  const float* gb1 = (const float*)d_in[2];   // [H]
  const float* gw2 = (const float*)d_in[3];   // [E,H]
  const float* gb2 = (const float*)d_in[4];   // [E]
  const float* bw1 = (const float*)d_in[5];   // [F,H]
  const float* bb1 = (const float*)d_in[6];   // [F]
  const float* bw2 = (const float*)d_in[7];   // [H,F]
  const float* bb2 = (const float*)d_in[8];   // [H]
  const float* tw1 = (const float*)d_in[9];   // [E,F,H]
  const float* tb1 = (const float*)d_in[10];  // [E,F]
  const float* tw2 = (const float*)d_in[11];  // [E,H,F]
  const float* tb2 = (const float*)d_in[12];  // [E,H]
  float* out = (float*)d_out;                 // [S,B,H]

  // one-time: allow >64KB dynamic LDS where needed
  static bool s_attr = false;
  if (!s_attr) {
    (void)hipFuncSetAttribute(
        reinterpret_cast<const void*>(gemm2p<0, 128, 128, 2, 2, 4>),
        hipFuncAttributeMaxDynamicSharedMemorySize, 65536);
    (void)hipFuncSetAttribute(
        reinterpret_cast<const void*>(gemm2p<2, 128, 128, 2, 2, 4>),
        hipFuncAttributeMaxDynamicSharedMemorySize, 65536);
    (void)hipFuncSetAttribute(
        reinterpret_cast<const void*>(gemm2p<1, 256, 128, 4, 2, 3>),
        hipFuncAttributeMaxDynamicSharedMemorySize, 73728);
    s_attr = true;
  }

  // workspace carve (256B aligned)
  size_t off = 0;
  auto carve = [&](size_t bytes) -> void* {
    void* p = (char*)d_ws + off;
    off += (bytes + 255) & ~(size_t)255;
    return p;
  };
  ushort* Xbf   = (ushort*)carve((size_t)SB * HDIM * 2);     // X in bf16
  ushort* gw1bf = (ushort*)carve((size_t)HDIM * HDIM * 2);   // gate w1 bf16
  ushort* w1m   = (ushort*)carve((size_t)FDIM * HDIM * 2);   // merged w1 bf16
  ushort* w2m   = (ushort*)carve((size_t)HDIM * FDIM * 2);   // merged w2 bf16
  ushort* hbuf  = (ushort*)carve((size_t)SB * FDIM * 2);     // h bf16
  float* b1m    = (float*)carve(FDIM * 4);
  float* b2m    = (float*)carve(HDIM * 4);
  float* colsum = (float*)carve(HDIM * 4);
  float* lam    = (float*)carve(EDIM * 4);

  // 1) prep: cast X + gw1 to bf16, zero colsum (1 launch)
  {
    constexpr int n4tot = SB * HDIM / 4 + HDIM * HDIM / 4;
    prep_kernel<<<(n4tot + 255) / 256, 256, 0, stream>>>(
        (const float4*)X, (ushort4*)Xbf, (const float4*)gw1, (ushort4*)gw1bf,
        colsum);
  }

  // 2) gate GEMM -> relu -> column sums (M=8192, N=1024, K=1024), 128x128/4w
  gemm2p<0, 128, 128, 2, 2, 4><<<dim3(HDIM / 128, SB / 128), 256, 65536,
                                 stream>>>(
      Xbf, gw1bf, gb1, colsum, SB, HDIM, HDIM);

  // 3) lambda
  lam_kernel<<<1, 256, 0, stream>>>(colsum, gw2, gb2, lam);

  // 4) merge weights + biases
  {
    int n4 = FDIM * HDIM / 4;
    merge_w_kernel<<<(n4 + 255) / 256, 256, 0, stream>>>(
        (const float4*)bw1, (const float4*)tw1, lam, (ushort4*)w1m, n4);
    merge_w_kernel<<<(n4 + 255) / 256, 256, 0, stream>>>(
        (const float4*)bw2, (const float4*)tw2, lam, (ushort4*)w2m, n4);
    merge_b_both<<<(FDIM + HDIM + 255) / 256, 256, 0, stream>>>(
        bb1, tb1, b1m, bb2, tb2, b2m, lam);
  }

  // 5) h = relu(X @ w1m^T + b1m) (M=8192, N=4096, K=1024), 256x128/8w
  gemm2p<1, 256, 128, 4, 2, 3><<<dim3(FDIM / 128, SB / 256), 512, 73728,
                                 stream>>>(
      Xbf, w1m, b1m, hbuf, SB, FDIM, HDIM);

  // 6) out = h @ w2m^T + b2m (M=8192, N=1024, K=4096), 128x128/4w
  gemm2p<2, 128, 128, 2, 2, 4><<<dim3(HDIM / 128, SB / 128), 256, 65536,
                                 stream>>>(
      hbuf, w2m, b2m, out, SB, HDIM, FDIM);
}

// Round 9
// 539.008 us; speedup vs baseline: 1.9664x; 1.0202x over previous
//
#include <hip/hip_runtime.h>
#include <hip/hip_bf16.h>
#include <stdint.h>
#include <type_traits>

// Problem constants (S=2048, B=4, H=1024, F=4096, E=8)
#define SB   8192
#define HDIM 1024
#define FDIM 4096
#define EDIM 8

typedef __bf16 bf16x8 __attribute__((ext_vector_type(8)));
typedef float  f32x4  __attribute__((ext_vector_type(4)));

__device__ __forceinline__ void g2l16(const void* g, void* l) {
  __builtin_amdgcn_global_load_lds(
      (const __attribute__((address_space(1))) uint32_t*)g,
      (__attribute__((address_space(3))) uint32_t*)l, 16, 0, 0);
}

__device__ __forceinline__ unsigned short f2bf(float f) {
  __hip_bfloat16 b = __float2bfloat16(f);
  return *reinterpret_cast<unsigned short*>(&b);
}

// inline-asm ds_read_b128 with compile-time offset immediate.
template <int IMM>
__device__ __forceinline__ bf16x8 lds_rd128(int addr) {
  static_assert(IMM >= 0 && IMM < 65536, "ds offset");
  bf16x8 r;
  asm volatile("ds_read_b128 %0, %1 offset:%2" : "=v"(r) : "v"(addr), "n"(IMM));
  return r;
}

// ---------------- prep: cast X + gw1 to bf16, zero colsum (grid-stride) ----
__global__ void prep_kernel(const float4* __restrict__ X,
                            ushort4* __restrict__ Xbf,
                            const float4* __restrict__ gw1,
                            ushort4* __restrict__ gw1bf,
                            float* __restrict__ colsum) {
  constexpr int n4x = SB * HDIM / 4;
  constexpr int n4g = HDIM * HDIM / 4;
  constexpr int total = n4x + n4g;
  const int tid0 = blockIdx.x * blockDim.x + threadIdx.x;
  const int stride = gridDim.x * blockDim.x;
  if (tid0 < HDIM) colsum[tid0] = 0.f;
  for (int i = tid0; i < total; i += stride) {
    const bool fx = i < n4x;
    const int j = fx ? i : i - n4x;
    const float4 v = fx ? X[j] : gw1[j];
    ushort4 o;
    o.x = f2bf(v.x); o.y = f2bf(v.y); o.z = f2bf(v.z); o.w = f2bf(v.w);
    if (fx) Xbf[j] = o; else gw1bf[j] = o;
  }
}

// ---------------- lambda: one block per expert, wave-shuffle reduce --------
__global__ void lam_kernel(const float* __restrict__ colsum,
                           const float* __restrict__ gw2,
                           const float* __restrict__ gb2,
                           float* __restrict__ lam) {
  const int e = blockIdx.x;
  const int tid = threadIdx.x;
  __shared__ float red[4];
  float p = 0.f;
  for (int h = tid; h < HDIM; h += 256) p += colsum[h] * gw2[e * HDIM + h];
#pragma unroll
  for (int off = 32; off > 0; off >>= 1) p += __shfl_down(p, off);
  if ((tid & 63) == 0) red[tid >> 6] = p;
  __syncthreads();
  if (tid == 0)
    lam[e] = gb2[e] + (red[0] + red[1] + red[2] + red[3]) * (1.f / 8192.f);
}

// ---------------- merge_all: both weight merges + both bias merges ---------
// Single big dispatch (~300MB traffic) so it ranks in the top-5 profile
// table: direct BW measurement of the streaming path.
__global__ void merge_all(const float4* __restrict__ bw1,
                          const float4* __restrict__ tw1,
                          ushort4* __restrict__ w1m,
                          const float4* __restrict__ bw2,
                          const float4* __restrict__ tw2,
                          ushort4* __restrict__ w2m,
                          const float* __restrict__ bb1,
                          const float* __restrict__ tb1,
                          float* __restrict__ b1m,
                          const float* __restrict__ bb2,
                          const float* __restrict__ tb2,
                          float* __restrict__ b2m,
                          const float* __restrict__ lam) {
  constexpr int n4 = FDIM * HDIM / 4;
  float l[EDIM];
#pragma unroll
  for (int e = 0; e < EDIM; ++e) l[e] = lam[e];
  const int tid0 = blockIdx.x * blockDim.x + threadIdx.x;
  // biases (once; grid is large enough: 2048*256 >= FDIM+HDIM)
  if (tid0 < FDIM) {
    float v = bb1[tid0];
#pragma unroll
    for (int e = 0; e < EDIM; ++e) v += l[e] * tb1[e * FDIM + tid0];
    b1m[tid0] = v;
  } else if (tid0 < FDIM + HDIM) {
    const int j = tid0 - FDIM;
    float v = bb2[j];
#pragma unroll
    for (int e = 0; e < EDIM; ++e) v += l[e] * tb2[e * HDIM + j];
    b2m[j] = v;
  }
  // weights: grid-stride, lane-contiguous float4 (proven-coalesced pattern)
  const int stride = gridDim.x * blockDim.x;
  for (int i = tid0; i < 2 * n4; i += stride) {
    const bool first = i < n4;
    const int j = first ? i : i - n4;
    const float4* bp = first ? bw1 : bw2;
    const float4* tp = first ? tw1 : tw2;
    float4 v = bp[j];
#pragma unroll
    for (int e = 0; e < EDIM; ++e) {
      const float4 t = tp[(size_t)e * n4 + j];
      v.x += l[e] * t.x; v.y += l[e] * t.y; v.z += l[e] * t.z; v.w += l[e] * t.w;
    }
    ushort4 o;
    o.x = f2bf(v.x); o.y = f2bf(v.y); o.z = f2bf(v.z); o.w = f2bf(v.w);
    if (first) w1m[j] = o; else w2m[j] = o;
  }
}

// ---------------------------------------------------------------------------
// gemm2p: ring-buffer pipelined MFMA bt-GEMM.  C[M,N] = A[M,K]*B[N,K]^T
// R8 verdict (kept frozen): every geometry in this 1-barrier-per-BK family
// lands at ~810 TF (1594cy per 128^2-iter, 3185cy per 256x128-iter,
// scheduling-invariant) -- structural ceiling.  Config: 64x64 wave tiles,
//   * 512-thr (WR4xWC2) 256x128 tile, RING=3 (72KB, 2 blocks/CU) - GEMM6.
//   * 256-thr (WR2xWC2) 128x128 tile, RING=4 (64KB, 2 blocks/CU) - gate,G7.
// BK=32; iter j stages tile j+RING-1 into the slot read at iter j-1 (drained
// by lgkmcnt(0)+barrier there); confirm of tile j+1 waits vmcnt(ahead*LPI)
// counted, never 0 until the tail.  Swizzled content via pre-swizzled global
// source + lane-linear LDS dest (rule 21); asm ds_read imm offsets.
// MODE 0: bias+relu colsum atomicAdd.  1: bias+relu bf16.  2: bias fp32.
template <int MODE, int BM, int BN, int WR, int WC, int RING>
__global__ void __launch_bounds__(WR * WC * 64, 4)
gemm2p(const ushort* __restrict__ A, const ushort* __restrict__ B,
       const float* __restrict__ bias, void* __restrict__ Cout,
       int M, int N, int K) {
  constexpr int THREADS = WR * WC * 64;
  constexpr int MI = (BM / WR) / 16;
  constexpr int NI = (BN / WC) / 16;
  static_assert(MI == 4 && NI == 4, "64x64 wave tile expected");
  constexpr int RPU = THREADS / 4;        // rows per g2l16 unit
  constexpr int UA  = BM / RPU;           // A units per tile
  constexpr int UB  = BN / RPU;           // B units per tile
  constexpr int LPI = UA + UB;            // loads per tile
  constexpr int AR_E = BM * 32;           // A slot elems
  constexpr int BR_E = BN * 32;           // B slot elems
  constexpr int ASB  = BM * 64;           // A slot bytes
  constexpr int BSB  = BN * 64;           // B slot bytes
  extern __shared__ __align__(16) ushort smem[];
  (void)M;

  const int tid  = threadIdx.x;
  const int lane = tid & 63;
  const int wave = tid >> 6;
  const int wm = wave / WC, wn = wave % WC;
  const int lr = lane & 15, lq = lane >> 4;

  // XCD-aware swizzle (gridDim.y % 8 == 0)
  const int bid = blockIdx.y * gridDim.x + blockIdx.x;
  const int gx  = gridDim.x;
  const int Yc  = gridDim.y >> 3;
  const int xcd = bid & 7;
  const int tt  = bid >> 3;
  const int tq  = tt / gx;
  const int ty  = xcd * Yc + tq;
  const int tx  = tt - tq * gx;
  const int m0 = ty * BM, n0 = tx * BN;

  const int NT = K >> 5;  // BK=32 steps

  // ---- LDS read bases (swizzle term lane-constant: row steps of 16)
  const uint32_t smemBase =
      (uint32_t)(uintptr_t)(__attribute__((address_space(3))) ushort*)smem;
  const int rowAl = wm * (BM / WR) + lr;
  const int vA = (int)smemBase + rowAl * 64 + ((lq ^ ((rowAl >> 1) & 3)) << 4);
  const int rowBl = wn * (BN / WC) + lr;
  const int vB = (int)smemBase + RING * ASB + rowBl * 64 +
                 ((lq ^ ((rowBl >> 1) & 3)) << 4);

  // ---- staging pointers (global src pre-swizzled, LDS dest lane-linear).
  const int rr = tid >> 2;
  const int colS = ((tid & 3) ^ ((rr >> 1) & 3)) * 8;
  const ushort* gAp = A + (size_t)(m0 + rr) * K + colS;
  const ushort* gBp = B + (size_t)(n0 + rr) * K + colS;
  ushort* lds0 = smem + tid * 8;

  f32x4 acc[4][4];
#pragma unroll
  for (int i = 0; i < 4; ++i)
#pragma unroll
    for (int n = 0; n < 4; ++n)
#pragma unroll
      for (int r = 0; r < 4; ++r) acc[i][n][r] = 0.f;

  // stage one K-step tile into ring slot
  auto stage = [&](int slot, int kt) {
    const int kk = kt * 32;
#pragma unroll
    for (int u = 0; u < UA; ++u)
      g2l16(gAp + (size_t)u * RPU * K + kk, lds0 + slot * AR_E + u * RPU * 32);
#pragma unroll
    for (int u = 0; u < UB; ++u)
      g2l16(gBp + (size_t)u * RPU * K + kk,
            lds0 + RING * AR_E + slot * BR_E + u * RPU * 32);
  };

  // ---- prologue: tiles 0..RING-2; confirm tile 0
#pragma unroll
  for (int r = 0; r < RING - 1; ++r) stage(r, r);
  __builtin_amdgcn_sched_barrier(0);
  asm volatile("s_waitcnt vmcnt(%0)" ::"n"((RING - 2) * LPI));
  __builtin_amdgcn_s_barrier();
  __builtin_amdgcn_sched_barrier(0);

  int rdSlot = 0, stSlot = RING - 1, stTile = RING - 1;
  for (int j = 0; j < NT; ++j) {
    if (stTile < NT) stage(stSlot, stTile);
    __builtin_amdgcn_sched_barrier(0);
    // fragment reads (asm, imm offsets off runtime ring base)
    const int aB = vA + rdSlot * ASB;
    const int bB = vB + rdSlot * BSB;
    bf16x8 bfr[4], afr[4];
    bfr[0] = lds_rd128<0>(bB);
    bfr[1] = lds_rd128<1024>(bB);
    bfr[2] = lds_rd128<2048>(bB);
    bfr[3] = lds_rd128<3072>(bB);
    afr[0] = lds_rd128<0>(aB);
    afr[1] = lds_rd128<1024>(aB);
    afr[2] = lds_rd128<2048>(aB);
    afr[3] = lds_rd128<3072>(aB);
    asm volatile("s_waitcnt lgkmcnt(0)");
    __builtin_amdgcn_sched_barrier(0);
    __builtin_amdgcn_s_setprio(1);
#pragma unroll
    for (int i = 0; i < 4; ++i)
#pragma unroll
      for (int n = 0; n < 4; ++n)
        acc[i][n] = __builtin_amdgcn_mfma_f32_16x16x32_bf16(
            afr[i], bfr[n], acc[i][n], 0, 0, 0);
    __builtin_amdgcn_s_setprio(0);
    __builtin_amdgcn_sched_barrier(0);
    // confirm tile j+1 resident (counted; issued RING-2 iters earlier)
    if (j + 1 < NT) {
      const int ls = stTile < NT ? stTile : NT - 1;
      const int ahead = ls - (j + 1);
      if constexpr (RING == 3) {
        if (ahead >= 1) asm volatile("s_waitcnt vmcnt(%0)" ::"n"(LPI));
        else            asm volatile("s_waitcnt vmcnt(0)");
      } else {  // RING == 4
        if (ahead >= 2)      asm volatile("s_waitcnt vmcnt(%0)" ::"n"(2 * LPI));
        else if (ahead == 1) asm volatile("s_waitcnt vmcnt(%0)" ::"n"(LPI));
        else                 asm volatile("s_waitcnt vmcnt(0)");
      }
    }
    __builtin_amdgcn_s_barrier();
    __builtin_amdgcn_sched_barrier(0);
    rdSlot = (rdSlot + 1 == RING) ? 0 : rdSlot + 1;
    stSlot = (stSlot + 1 == RING) ? 0 : stSlot + 1;
    ++stTile;
  }

  // ---- epilogue.  C/D layout (verified m89/m91): col=ni*16+lr, row=lq*4+r.
  const int gm = m0 + wm * (BM / WR);
  const int gn = n0 + wn * (BN / WC);
  if constexpr (MODE == 0) {
    float* colsum = (float*)Cout;
#pragma unroll
    for (int ni = 0; ni < 4; ++ni) {
      const int col = gn + ni * 16 + lr;
      const float bv = bias[col];
      float p = 0.f;
#pragma unroll
      for (int mi = 0; mi < 4; ++mi)
#pragma unroll
        for (int r = 0; r < 4; ++r) {
          float v = acc[mi][ni][r] + bv;
          p += v > 0.f ? v : 0.f;
        }
      p += __shfl_xor(p, 16);
      p += __shfl_xor(p, 32);
      if (lq == 0) atomicAdd(&colsum[col], p);
    }
  } else if constexpr (MODE == 1) {
    __hip_bfloat16* C = (__hip_bfloat16*)Cout;
#pragma unroll
    for (int ni = 0; ni < 4; ++ni) {
      const int col = gn + ni * 16 + lr;
      const float bv = bias[col];
#pragma unroll
      for (int mi = 0; mi < 4; ++mi)
#pragma unroll
        for (int r = 0; r < 4; ++r) {
          const int row = gm + mi * 16 + lq * 4 + r;
          float v = acc[mi][ni][r] + bv;
          v = v > 0.f ? v : 0.f;
          C[(size_t)row * N + col] = __float2bfloat16(v);
        }
    }
  } else {
    float* C = (float*)Cout;
#pragma unroll
    for (int ni = 0; ni < 4; ++ni) {
      const int col = gn + ni * 16 + lr;
      const float bv = bias[col];
#pragma unroll
      for (int mi = 0; mi < 4; ++mi)
#pragma unroll
        for (int r = 0; r < 4; ++r) {
          const int row = gm + mi * 16 + lq * 4 + r;
          C[(size_t)row * N + col] = acc[mi][ni][r] + bv;
        }
    }
  }
}

// ---------------------------------------------------------------------------
extern "C" void kernel_launch(void* const* d_in, const int* in_sizes, int n_in,
                              void* d_out, int out_size, void* d_ws, size_t ws_size,
                              hipStream_t stream) {
  const float* X   = (const float*)d_in[0];   // [S,B,H]
  const float* gw1 = (const float*)d_in[1];   // [H,H]
  const float* gb1 = (const float*)d_in[2];   // [H]
  const float* gw2 = (const float*)d_in[3];   // [E,H]
  const float* gb2 = (const float*)d_in[4];   // [E]
  const float* bw1 = (const float*)d_in[5];   // [F,H]
  const float* bb1 = (const float*)d_in[6];   // [F]
  const float* bw2 = (const float*)d_in[7];   // [H,F]
  const float* bb2 = (const float*)d_in[8];   // [H]
  const float* tw1 = (const float*)d_in[9];   // [E,F,H]
  const float* tb1 = (const float*)d_in[10];  // [E,F]
  const float* tw2 = (const float*)d_in[11];  // [E,H,F]
  const float* tb2 = (const float*)d_in[12];  // [E,H]
  float* out = (float*)d_out;                 // [S,B,H]

  // one-time: allow >64KB dynamic LDS where needed
  static bool s_attr = false;
  if (!s_attr) {
    (void)hipFuncSetAttribute(
        reinterpret_cast<const void*>(gemm2p<0, 128, 128, 2, 2, 4>),
        hipFuncAttributeMaxDynamicSharedMemorySize, 65536);
    (void)hipFuncSetAttribute(
        reinterpret_cast<const void*>(gemm2p<2, 128, 128, 2, 2, 4>),
        hipFuncAttributeMaxDynamicSharedMemorySize, 65536);
    (void)hipFuncSetAttribute(
        reinterpret_cast<const void*>(gemm2p<1, 256, 128, 4, 2, 3>),
        hipFuncAttributeMaxDynamicSharedMemorySize, 73728);
    s_attr = true;
  }

  // workspace carve (256B aligned)
  size_t off = 0;
  auto carve = [&](size_t bytes) -> void* {
    void* p = (char*)d_ws + off;
    off += (bytes + 255) & ~(size_t)255;
    return p;
  };
  ushort* Xbf   = (ushort*)carve((size_t)SB * HDIM * 2);     // X in bf16
  ushort* gw1bf = (ushort*)carve((size_t)HDIM * HDIM * 2);   // gate w1 bf16
  ushort* w1m   = (ushort*)carve((size_t)FDIM * HDIM * 2);   // merged w1 bf16
  ushort* w2m   = (ushort*)carve((size_t)HDIM * FDIM * 2);   // merged w2 bf16
  ushort* hbuf  = (ushort*)carve((size_t)SB * FDIM * 2);     // h bf16
  float* b1m    = (float*)carve(FDIM * 4);
  float* b2m    = (float*)carve(HDIM * 4);
  float* colsum = (float*)carve(HDIM * 4);
  float* lam    = (float*)carve(EDIM * 4);

  // 1) prep: cast X + gw1 to bf16, zero colsum (grid-stride, 2048 blocks)
  prep_kernel<<<2048, 256, 0, stream>>>(
      (const float4*)X, (ushort4*)Xbf, (const float4*)gw1, (ushort4*)gw1bf,
      colsum);

  // 2) gate GEMM -> relu -> column sums (M=8192, N=1024, K=1024), 128x128/4w
  gemm2p<0, 128, 128, 2, 2, 4><<<dim3(HDIM / 128, SB / 128), 256, 65536,
                                 stream>>>(
      Xbf, gw1bf, gb1, colsum, SB, HDIM, HDIM);

  // 3) lambda (8 blocks, one per expert)
  lam_kernel<<<EDIM, 256, 0, stream>>>(colsum, gw2, gb2, lam);

  // 4) merge weights + biases in ONE dispatch (~300MB: top-5-visible)
  merge_all<<<2048, 256, 0, stream>>>(
      (const float4*)bw1, (const float4*)tw1, (ushort4*)w1m,
      (const float4*)bw2, (const float4*)tw2, (ushort4*)w2m,
      bb1, tb1, b1m, bb2, tb2, b2m, lam);

  // 5) h = relu(X @ w1m^T + b1m) (M=8192, N=4096, K=1024), 256x128/8w
  gemm2p<1, 256, 128, 4, 2, 3><<<dim3(FDIM / 128, SB / 256), 512, 73728,
                                 stream>>>(
      Xbf, w1m, b1m, hbuf, SB, FDIM, HDIM);

  // 6) out = h @ w2m^T + b2m (M=8192, N=1024, K=4096), 128x128/4w
  gemm2p<2, 128, 128, 2, 2, 4><<<dim3(HDIM / 128, SB / 128), 256, 65536,
                                 stream>>>(
      hbuf, w2m, b2m, out, SB, HDIM, FDIM);
}